// Round 14
// baseline (121.400 us; speedup 1.0000x reference)
//
#include <hip/hip_runtime.h>
#include <hip/hip_bf16.h>
#include <math.h>

#define BB 4
#define CC 64
#define DD 8
#define NN 4096
#define KS 8
#define KPS (NN / KS)          // 512 keys per split = 2 stages of 256
#define KSTR 12                // KL row stride (elems): 2-way-free kf reads
#define LOG2E 1.44269504088896340736f

typedef __attribute__((ext_vector_type(4))) short short4v;      // 4 bf16
typedef __attribute__((ext_vector_type(4))) unsigned short ushort4v;
typedef __attribute__((ext_vector_type(8))) unsigned short ushort8;  // 16B
typedef __attribute__((ext_vector_type(16))) float f32x16;

#if defined(__HIP_DEVICE_COMPILE__)
  #if __has_builtin(__builtin_amdgcn_mfma_f32_32x32x8bf16_1k)
    #define MFMA32x8(A, B, C) __builtin_amdgcn_mfma_f32_32x32x8bf16_1k(A, B, C, 0, 0, 0)
  #elif __has_builtin(__builtin_amdgcn_mfma_f32_32x32x8_bf16)
    #define MFMA32x8(A, B, C) __builtin_amdgcn_mfma_f32_32x32x8_bf16(A, B, C, 0, 0, 0)
  #else
    #error "no 32x32x8 bf16 MFMA builtin in device pass"
  #endif
  #if __has_builtin(__builtin_amdgcn_exp2f)
    #define EXP2(x) __builtin_amdgcn_exp2f(x)
  #else
    #define EXP2(x) exp2f(x)
  #endif
#else
  static __device__ __host__ inline f32x16 MFMA32x8(short4v, short4v, f32x16 c) { return c; }
  #define EXP2(x) exp2f(x)
#endif

// Direct global->LDS DMA (16B/lane, dest = wave-uniform base + lane*16).
// Fallback (host pass / missing builtin): manual lane-addressed copy.
static __device__ __forceinline__ void gll16(const unsigned short* g,
                                             unsigned short* l, int lane) {
#if defined(__HIP_DEVICE_COMPILE__) && __has_builtin(__builtin_amdgcn_global_load_lds)
    __builtin_amdgcn_global_load_lds(
        (const __attribute__((address_space(1))) unsigned int*)g,
        (__attribute__((address_space(3))) unsigned int*)l, 16, 0, 0);
    (void)lane;
#else
    *(ushort8*)((char*)l + (size_t)lane * 16) = *(const ushort8*)g;
#endif
}

static __device__ inline short4v pack4(float a, float b, float c, float d) {
    union { short4v s; __hip_bfloat162 h[2]; } u;
    u.h[0] = __float22bfloat162_rn(make_float2(a, b));
    u.h[1] = __float22bfloat162_rn(make_float2(c, d));
    return u.s;
}
static __device__ inline unsigned packu(float lo, float hi) {
    union { __hip_bfloat162 h; unsigned u; } t;
    t.h = __float22bfloat162_rn(make_float2(lo, hi));
    return t.u;
}

// ---------------------------------------------------------------------------
// Kernel 1: qkv as MFMA GEMM (unchanged from R8-R13).
// ---------------------------------------------------------------------------
__global__ __launch_bounds__(256) void qkv_kernel(
    const float* __restrict__ x,  const float* __restrict__ Wq, const float* __restrict__ bq,
    const float* __restrict__ Wk, const float* __restrict__ bk,
    const float* __restrict__ Wv, const float* __restrict__ bv,
    unsigned short* __restrict__ qb, unsigned short* __restrict__ kb,
    unsigned short* __restrict__ vT)
{
    __shared__ unsigned short LQ[128 * 8];
    __shared__ unsigned short LK[128 * 8];

    int tid = threadIdx.x;
    int wave = tid >> 6, lane = tid & 63;
    int l32 = lane & 31, h2 = lane >> 5;

    int blk = blockIdx.x;
    int b = blk & (BB - 1);
    int r2 = blk >> 2;
    int rt = r2 % 3;
    int ng = r2 / 3;
    int n0 = ng * 128 + wave * 32;

    short4v af[8];
    #pragma unroll
    for (int s = 0; s < 8; ++s) {
        float4 w4;
        if (rt < 2) {
            w4 = *(const float4*)(Wv + (size_t)(rt * 32 + l32) * CC + s * 8 + 4 * h2);
        } else if (l32 < 8) {
            w4 = *(const float4*)(Wq + (size_t)l32 * CC + s * 8 + 4 * h2);
        } else if (l32 < 16) {
            w4 = *(const float4*)(Wk + (size_t)(l32 - 8) * CC + s * 8 + 4 * h2);
        } else {
            w4 = make_float4(0.f, 0.f, 0.f, 0.f);
        }
        af[s] = pack4(w4.x, w4.y, w4.z, w4.w);
    }

    const float* xb = x + (size_t)b * CC * NN + n0 + l32;
    short4v bf[8];
    #pragma unroll
    for (int s = 0; s < 8; ++s) {
        int c0 = s * 8 + 4 * h2;
        float x0 = xb[(size_t)(c0 + 0) * NN];
        float x1 = xb[(size_t)(c0 + 1) * NN];
        float x2 = xb[(size_t)(c0 + 2) * NN];
        float x3 = xb[(size_t)(c0 + 3) * NN];
        bf[s] = pack4(x0, x1, x2, x3);
    }

    f32x16 acc;
    #pragma unroll
    for (int r = 0; r < 16; ++r) acc[r] = 0.f;
    #pragma unroll
    for (int s = 0; s < 8; ++s)
        acc = MFMA32x8(af[s], bf[s], acc);

    if (rt < 2) {
        #pragma unroll
        for (int r = 0; r < 16; ++r) {
            int row = rt * 32 + (r & 3) + 8 * (r >> 2) + 4 * h2;
            float val = acc[r] + bv[row];
            __hip_bfloat16 hv = __float2bfloat16(val);
            vT[((size_t)b * CC + row) * NN + n0 + l32] = *(unsigned short*)&hv;
        }
    } else {
        short4v qp = pack4((acc[0] + bq[0 + 4 * h2]) * LOG2E,
                           (acc[1] + bq[1 + 4 * h2]) * LOG2E,
                           (acc[2] + bq[2 + 4 * h2]) * LOG2E,
                           (acc[3] + bq[3 + 4 * h2]) * LOG2E);
        short4v kp = pack4(acc[4] + bk[0 + 4 * h2],
                           acc[5] + bk[1 + 4 * h2],
                           acc[6] + bk[2 + 4 * h2],
                           acc[7] + bk[3 + 4 * h2]);
        int nl = wave * 32 + l32;
        *(short4v*)(LQ + (size_t)nl * 8 + 4 * h2) = qp;
        *(short4v*)(LK + (size_t)nl * 8 + 4 * h2) = kp;
        __syncthreads();
        if (tid < 128) {
            ushort8 row = *(const ushort8*)(LQ + (size_t)tid * 8);
            *(ushort8*)(qb + ((size_t)b * NN + ng * 128 + tid) * 8) = row;
        } else {
            int t = tid - 128;
            ushort8 row = *(const ushort8*)(LK + (size_t)t * 8);
            *(ushort8*)(kb + ((size_t)b * NN + ng * 128 + t) * 8) = row;
        }
    }
}

// ---------------------------------------------------------------------------
// Kernel 2: MFMA flash with global_load_lds V-staging (no VGPR round-trip).
// VS rows are UNPADDED 512B (lane-linear DMA dest); the bank catastrophe
// (32-way on channel-parallel reads) is avoided by XOR-swizzling the SOURCE
// address per lane (granule l32 holds logical l32^(ch&7)) -> reads 4-way
// (1.58x, cheap).  K staged manually into padded KSTR=12 (2-way-free).
// KS=8: two 256-key stages, LDS double-buffered; stage-1 DMA issues right
// after barrier-1 and drains under stage-0 compute; 2 barriers total.
// 76KB LDS -> 2 blocks/CU x 8 waves = 16 waves/CU; (512,4) -> no spills.
// Grid: BB * 16 qchunks * KS = 512 blocks (1 full round at 2/CU).
// ---------------------------------------------------------------------------
static __device__ __forceinline__ void compute_stage(
    const unsigned short* VSst, const unsigned short* KLst,
    short4v qf, int l32, int h2,
    f32x16& o0, f32x16& o1, float& s0, float& s1, float& s2, float& s3)
{
    f32x16 zz;
    #pragma unroll
    for (int r = 0; r < 16; ++r) zz[r] = 0.f;
    #pragma unroll
    for (int s = 0; s < 8; ++s) {
        short4v kf = *(const short4v*)(KLst + (size_t)(s * 32 + l32) * KSTR + h2 * 4);
        f32x16 st = MFMA32x8(kf, qf, zz);
        float w[16];
        #pragma unroll
        for (int r = 0; r < 16; ++r) w[r] = EXP2(st[r]);
        s0 += (w[0] + w[1]) + (w[2] + w[3]);
        s1 += (w[4] + w[5]) + (w[6] + w[7]);
        s2 += (w[8] + w[9]) + (w[10] + w[11]);
        s3 += (w[12] + w[13]) + (w[14] + w[15]);

        union { short4v s; __hip_bfloat162 h[2]; } u[4];
        #pragma unroll
        for (int g = 0; g < 4; ++g) {
            u[g].h[0] = __float22bfloat162_rn(make_float2(w[4 * g],     w[4 * g + 1]));
            u[g].h[1] = __float22bfloat162_rn(make_float2(w[4 * g + 2], w[4 * g + 3]));
        }
        #pragma unroll
        for (int g = 0; g < 4; ++g) {
            int go = (((s * 4 + g) ^ (l32 & 7)) * 8) + h2 * 4;   // XOR-swizzled
            short4v vf0 = *(const short4v*)(VSst + (size_t)(l32)      * 256 + go);
            short4v vf1 = *(const short4v*)(VSst + (size_t)(32 + l32) * 256 + go);
            o0 = MFMA32x8(u[g].s, vf0, o0);
            o1 = MFMA32x8(u[g].s, vf1, o1);
        }
    }
}

__global__ __launch_bounds__(512, 4) void flash_kernel(
    const unsigned short* __restrict__ qb, const unsigned short* __restrict__ kb,
    const unsigned short* __restrict__ vT, unsigned* __restrict__ accb,
    float* __restrict__ sbuf)
{
    __shared__ unsigned short VS[2][64 * 256];   // 2 x 32KB, unpadded rows
    __shared__ unsigned short KL[2][256 * KSTR]; // 2 x 6KB, padded rows
    int tid = threadIdx.x;
    int wave = tid >> 6, lane = tid & 63;
    int l32 = lane & 31, h2 = lane >> 5;

    int blk = blockIdx.x;            // batch in low 2 bits -> XCD locality
    int b = blk & (BB - 1);
    int rest = blk >> 2;
    int split = rest & (KS - 1);
    int qchunk = rest >> 3;
    int n0 = qchunk * 256 + wave * 32;

    short4v qf = *(const short4v*)(qb + ((size_t)b * NN + n0 + l32) * DD + h2 * 4);

    const unsigned short* kbb = kb + (size_t)b * NN * DD;
    const unsigned short* vbb = vT + (size_t)b * CC * NN;
    int m0 = split * KPS;

    // per-lane DMA source offsets (stage-invariant): instr i covers channels
    // 8*wave+2i+h2; granule slot l32 sources logical granule l32^(ch&7).
    int chv[4], offv[4];
    #pragma unroll
    for (int i = 0; i < 4; ++i) {
        chv[i] = 8 * wave + 2 * i + h2;
        offv[i] = chv[i] * NN + 8 * (l32 ^ (chv[i] & 7));
    }

    // ---- stage 0: DMA V, manual K, barrier
    #pragma unroll
    for (int i = 0; i < 4; ++i)
        gll16(vbb + offv[i] + m0, &VS[0][(size_t)(wave * 4 + i) * 512], lane);
    if (tid < 256) {
        ushort8 kA = *(const ushort8*)(kbb + (size_t)(m0 + tid) * DD);
        unsigned short* p = &KL[0][(size_t)tid * KSTR];
        *(ushort4v*)(p)     = *(ushort4v*)&kA;
        *(ushort4v*)(p + 4) = *((ushort4v*)&kA + 1);
    }
    __syncthreads();                             // barrier 1: stage 0 ready

    // ---- prefetch stage 1 (DMA -> VS[1]; K to VGPR now, LDS after compute)
    ushort8 kB = {0,0,0,0,0,0,0,0};
    if (tid < 256) kB = *(const ushort8*)(kbb + (size_t)(m0 + 256 + tid) * DD);
    #pragma unroll
    for (int i = 0; i < 4; ++i)
        gll16(vbb + offv[i] + m0 + 256, &VS[1][(size_t)(wave * 4 + i) * 512], lane);

    f32x16 o0, o1;
    #pragma unroll
    for (int r = 0; r < 16; ++r) { o0[r] = 0.f; o1[r] = 0.f; }
    float s0 = 0.f, s1 = 0.f, s2 = 0.f, s3 = 0.f;

    compute_stage(VS[0], KL[0], qf, l32, h2, o0, o1, s0, s1, s2, s3);

    if (tid < 256) {                             // kB long since arrived
        unsigned short* p = &KL[1][(size_t)tid * KSTR];
        *(ushort4v*)(p)     = *(ushort4v*)&kB;
        *(ushort4v*)(p + 4) = *((ushort4v*)&kB + 1);
    }
    __syncthreads();                             // barrier 2: stage 1 ready

    compute_stage(VS[1], KL[1], qf, l32, h2, o0, o1, s0, s1, s2, s3);

    // ---- raw-layout full-line stores: uint = bf162(o0[r],o1[r])
    unsigned* au = accb + (((size_t)((b * KS + split) * 128 + qchunk * 8 + wave)) << 10);
    #pragma unroll
    for (int r = 0; r < 16; ++r)
        au[r * 64 + lane] = packu(o0[r], o1[r]);

    float ssum = (s0 + s1) + (s2 + s3);
    ssum += __shfl_xor(ssum, 32);
    if (lane < 32)
        sbuf[(size_t)(b * KS + split) * NN + n0 + l32] = ssum;
}

// ---------------------------------------------------------------------------
// Kernel 3: streaming split-reduce + normalize + residual (R13 structure,
// KS=8).  Contiguous uint4 reads; split-halves combined in LDS; coalesced
// out/x passes.  Grid: B*256 = 1024 blocks (16 queries each).
// ---------------------------------------------------------------------------
__global__ __launch_bounds__(256) void norm_kernel(
    const unsigned* __restrict__ accb, const float* __restrict__ sbuf,
    const float* __restrict__ x, const float* __restrict__ gamma,
    float* __restrict__ out)
{
    __shared__ float tile[16 * 65];
    __shared__ float stl[16];
    int blk = blockIdx.x;            // B * 256
    int b = blk >> 8;
    int h = blk & 255;
    int g32 = h >> 1;
    int qhalf = h & 1;
    int n0 = g32 * 32 + qhalf * 16;
    int tid = threadIdx.x;

    if (tid < 16) {
        float st = 0.f;
        #pragma unroll
        for (int sp = 0; sp < KS; ++sp)
            st += sbuf[(size_t)(b * KS + sp) * NN + n0 + tid];
        stl[tid] = 1.0f / st;
    }

    int spoff = tid >> 7;
    int u = tid & 127;
    int rl = u >> 4;
    int lane0 = (u & 15) * 4;

    float alo[4], ahi[4];
    #pragma unroll
    for (int e = 0; e < 4; ++e) { alo[e] = 0.f; ahi[e] = 0.f; }
    #pragma unroll
    for (int p = 0; p < KS / 2; ++p) {
        int sp = p * 2 + spoff;
        const unsigned* base = accb + (((size_t)((b * KS + sp) * 128 + g32)) << 10)
                             + qhalf * 512;
        uint4 v = *(const uint4*)(base + u * 4);
        unsigned wv[4] = {v.x, v.y, v.z, v.w};
        #pragma unroll
        for (int e = 0; e < 4; ++e) {
            alo[e] += __uint_as_float(wv[e] << 16);
            ahi[e] += __uint_as_float(wv[e] & 0xFFFF0000u);
        }
    }

    #pragma unroll
    for (int e = 0; e < 4; ++e) {
        int lane = lane0 + e;
        int h2 = lane >> 5, l32 = lane & 31;
        int ql = (rl & 3) + 8 * ((rl >> 2) & 1) + 4 * h2;
        if (tid < 128) {
            tile[ql * 65 + l32]      = alo[e];
            tile[ql * 65 + 32 + l32] = ahi[e];
        }
    }
    __syncthreads();
    #pragma unroll
    for (int e = 0; e < 4; ++e) {
        int lane = lane0 + e;
        int h2 = lane >> 5, l32 = lane & 31;
        int ql = (rl & 3) + 8 * ((rl >> 2) & 1) + 4 * h2;
        if (tid >= 128) {
            tile[ql * 65 + l32]      += alo[e];
            tile[ql * 65 + 32 + l32] += ahi[e];
        }
    }
    __syncthreads();

    float gm = gamma[0];
    #pragma unroll
    for (int p2 = 0; p2 < 4; ++p2) {
        int idx = p2 * 256 + tid;
        int c = idx >> 4, ql = idx & 15;
        size_t xi = ((size_t)b * CC + c) * NN + n0 + ql;
        out[xi] = gm * tile[ql * 65 + c] * stl[ql] + x[xi];
    }
}

// ---------------------------------------------------------------------------
extern "C" void kernel_launch(void* const* d_in, const int* in_sizes, int n_in,
                              void* d_out, int out_size, void* d_ws, size_t ws_size,
                              hipStream_t stream)
{
    const float* x     = (const float*)d_in[0];
    const float* Wq    = (const float*)d_in[1];
    const float* bq    = (const float*)d_in[2];
    const float* Wk    = (const float*)d_in[3];
    const float* bk    = (const float*)d_in[4];
    const float* Wv    = (const float*)d_in[5];
    const float* bv    = (const float*)d_in[6];
    const float* gamma = (const float*)d_in[7];
    float* out = (float*)d_out;

    float* ws = (float*)d_ws;
    size_t off = 0;
    unsigned short* qb = (unsigned short*)(ws + off); off += (size_t)BB * NN * DD / 2 + 64;
    unsigned short* kb = (unsigned short*)(ws + off); off += (size_t)BB * NN * DD / 2 + 64;
    unsigned short* vT = (unsigned short*)(ws + off); off += (size_t)BB * CC * NN / 2 + 64;
    unsigned* accb = (unsigned*)(ws + off); off += (size_t)BB * KS * NN * CC / 2;   // 16.8 MB
    float* sbuf = ws + off; off += (size_t)BB * KS * NN;

    qkv_kernel<<<BB * 3 * 32, 256, 0, stream>>>(x, Wq, bq, Wk, bk, Wv, bv, qb, kb, vT);
    flash_kernel<<<BB * 16 * KS, 512, 0, stream>>>(qb, kb, vT, accb, sbuf);
    norm_kernel<<<BB * 256, 256, 0, stream>>>(accb, sbuf, x, gamma, out);
}

// Round 15
// 101.738 us; speedup vs baseline: 1.1933x; 1.1933x over previous
//
#include <hip/hip_runtime.h>
#include <hip/hip_bf16.h>
#include <math.h>

#define BB 4
#define CC 64
#define DD 8
#define NN 4096
#define KS 16
#define KPS (NN / KS)          // 256 keys per split = ONE LDS stage
#define VSTR 260               // VS row stride (elems): 2-way-free b64 reads
#define KSTR 12                // KL row stride (elems)
#define LOG2E 1.44269504088896340736f

typedef __attribute__((ext_vector_type(4))) short short4v;      // 4 bf16
typedef __attribute__((ext_vector_type(4))) unsigned short ushort4v;
typedef __attribute__((ext_vector_type(8))) unsigned short ushort8;  // 16B
typedef __attribute__((ext_vector_type(16))) float f32x16;

#if defined(__HIP_DEVICE_COMPILE__)
  #if __has_builtin(__builtin_amdgcn_mfma_f32_32x32x8bf16_1k)
    #define MFMA32x8(A, B, C) __builtin_amdgcn_mfma_f32_32x32x8bf16_1k(A, B, C, 0, 0, 0)
  #elif __has_builtin(__builtin_amdgcn_mfma_f32_32x32x8_bf16)
    #define MFMA32x8(A, B, C) __builtin_amdgcn_mfma_f32_32x32x8_bf16(A, B, C, 0, 0, 0)
  #else
    #error "no 32x32x8 bf16 MFMA builtin in device pass"
  #endif
  #if __has_builtin(__builtin_amdgcn_exp2f)
    #define EXP2(x) __builtin_amdgcn_exp2f(x)
  #else
    #define EXP2(x) exp2f(x)
  #endif
#else
  static __device__ __host__ inline f32x16 MFMA32x8(short4v, short4v, f32x16 c) { return c; }
  #define EXP2(x) exp2f(x)
#endif

static __device__ inline short4v pack4(float a, float b, float c, float d) {
    union { short4v s; __hip_bfloat162 h[2]; } u;
    u.h[0] = __float22bfloat162_rn(make_float2(a, b));
    u.h[1] = __float22bfloat162_rn(make_float2(c, d));
    return u.s;
}
static __device__ inline unsigned packu(float lo, float hi) {
    union { __hip_bfloat162 h; unsigned u; } t;
    t.h = __float22bfloat162_rn(make_float2(lo, hi));
    return t.u;
}

// ---------------------------------------------------------------------------
// Kernel 1: qkv as MFMA GEMM (unchanged from R8-R13).
// ---------------------------------------------------------------------------
__global__ __launch_bounds__(256) void qkv_kernel(
    const float* __restrict__ x,  const float* __restrict__ Wq, const float* __restrict__ bq,
    const float* __restrict__ Wk, const float* __restrict__ bk,
    const float* __restrict__ Wv, const float* __restrict__ bv,
    unsigned short* __restrict__ qb, unsigned short* __restrict__ kb,
    unsigned short* __restrict__ vT)
{
    __shared__ unsigned short LQ[128 * 8];
    __shared__ unsigned short LK[128 * 8];

    int tid = threadIdx.x;
    int wave = tid >> 6, lane = tid & 63;
    int l32 = lane & 31, h2 = lane >> 5;

    int blk = blockIdx.x;
    int b = blk & (BB - 1);
    int r2 = blk >> 2;
    int rt = r2 % 3;
    int ng = r2 / 3;
    int n0 = ng * 128 + wave * 32;

    short4v af[8];
    #pragma unroll
    for (int s = 0; s < 8; ++s) {
        float4 w4;
        if (rt < 2) {
            w4 = *(const float4*)(Wv + (size_t)(rt * 32 + l32) * CC + s * 8 + 4 * h2);
        } else if (l32 < 8) {
            w4 = *(const float4*)(Wq + (size_t)l32 * CC + s * 8 + 4 * h2);
        } else if (l32 < 16) {
            w4 = *(const float4*)(Wk + (size_t)(l32 - 8) * CC + s * 8 + 4 * h2);
        } else {
            w4 = make_float4(0.f, 0.f, 0.f, 0.f);
        }
        af[s] = pack4(w4.x, w4.y, w4.z, w4.w);
    }

    const float* xb = x + (size_t)b * CC * NN + n0 + l32;
    short4v bf[8];
    #pragma unroll
    for (int s = 0; s < 8; ++s) {
        int c0 = s * 8 + 4 * h2;
        float x0 = xb[(size_t)(c0 + 0) * NN];
        float x1 = xb[(size_t)(c0 + 1) * NN];
        float x2 = xb[(size_t)(c0 + 2) * NN];
        float x3 = xb[(size_t)(c0 + 3) * NN];
        bf[s] = pack4(x0, x1, x2, x3);
    }

    f32x16 acc;
    #pragma unroll
    for (int r = 0; r < 16; ++r) acc[r] = 0.f;
    #pragma unroll
    for (int s = 0; s < 8; ++s)
        acc = MFMA32x8(af[s], bf[s], acc);

    if (rt < 2) {
        #pragma unroll
        for (int r = 0; r < 16; ++r) {
            int row = rt * 32 + (r & 3) + 8 * (r >> 2) + 4 * h2;
            float val = acc[r] + bv[row];
            __hip_bfloat16 hv = __float2bfloat16(val);
            vT[((size_t)b * CC + row) * NN + n0 + l32] = *(unsigned short*)&hv;
        }
    } else {
        short4v qp = pack4((acc[0] + bq[0 + 4 * h2]) * LOG2E,
                           (acc[1] + bq[1 + 4 * h2]) * LOG2E,
                           (acc[2] + bq[2 + 4 * h2]) * LOG2E,
                           (acc[3] + bq[3 + 4 * h2]) * LOG2E);
        short4v kp = pack4(acc[4] + bk[0 + 4 * h2],
                           acc[5] + bk[1 + 4 * h2],
                           acc[6] + bk[2 + 4 * h2],
                           acc[7] + bk[3 + 4 * h2]);
        int nl = wave * 32 + l32;
        *(short4v*)(LQ + (size_t)nl * 8 + 4 * h2) = qp;
        *(short4v*)(LK + (size_t)nl * 8 + 4 * h2) = kp;
        __syncthreads();
        if (tid < 128) {
            ushort8 row = *(const ushort8*)(LQ + (size_t)tid * 8);
            *(ushort8*)(qb + ((size_t)b * NN + ng * 128 + tid) * 8) = row;
        } else {
            int t = tid - 128;
            ushort8 row = *(const ushort8*)(LK + (size_t)t * 8);
            *(ushort8*)(kb + ((size_t)b * NN + ng * 128 + t) * 8) = row;
        }
    }
}

// ---------------------------------------------------------------------------
// Kernel 2: MFMA flash, SOFTWARE-PIPELINED subs (the R9-R14 invariant ~40us
// was the per-sub serial chain: ds_read kf -> QK MFMA -> exp -> pack -> PV,
// ~400-500 dependent cycles, unhidden at 4 waves/SIMD).  Now: all 8 kf
// preloaded to registers after the barrier; QK MFMA for sub s+1 issues
// BEFORE processing sub s, hiding MFMA latency under exp/pack/PV of the
// previous sub.  (512,4): 128-VGPR headroom for st0/st1 + kfr[8] (~110 live,
// no spill).  Single 256-key LDS stage (KS=16), 1 barrier, manual staging
// (VSTR=260 padded, 2-way-free reads), full-line raw-layout stores.
// Grid: BB * 16 qchunks * KS = 1024 blocks, 2/CU.
// ---------------------------------------------------------------------------
__global__ __launch_bounds__(512, 4) void flash_kernel(
    const unsigned short* __restrict__ qb, const unsigned short* __restrict__ kb,
    const unsigned short* __restrict__ vT, unsigned* __restrict__ accb,
    float* __restrict__ sbuf)
{
    __shared__ unsigned short VS[64 * VSTR];   // 256 keys x 64 ch, 33280 B
    __shared__ unsigned short KL[256 * KSTR];  //  6144 B
    int tid = threadIdx.x;
    int wave = tid >> 6, lane = tid & 63;
    int l32 = lane & 31, h2 = lane >> 5;

    int blk = blockIdx.x;            // batch in low 2 bits -> XCD locality
    int b = blk & (BB - 1);
    int rest = blk >> 2;
    int split = rest & (KS - 1);
    int qchunk = rest >> 4;
    int n0 = qchunk * 256 + wave * 32;

    short4v qf = *(const short4v*)(qb + ((size_t)b * NN + n0 + l32) * DD + h2 * 4);

    const unsigned short* kbb = kb + (size_t)b * NN * DD;
    const unsigned short* vbb = vT + (size_t)b * CC * NN;
    int m0 = split * KPS;

    // ---- stage: thread t -> channel t>>3, key segment (t&7)*32 (32 keys)
    int ch = tid >> 3, ks0 = (tid & 7) * 32;
    {
        const unsigned short* vg = vbb + (size_t)ch * NN + m0 + ks0;
        ushort8 v0 = *(const ushort8*)(vg);
        ushort8 v1 = *(const ushort8*)(vg + 8);
        ushort8 v2 = *(const ushort8*)(vg + 16);
        ushort8 v3 = *(const ushort8*)(vg + 24);
        ushort8 kA = {0,0,0,0,0,0,0,0};
        if (tid < 256) kA = *(const ushort8*)(kbb + (size_t)(m0 + tid) * DD);

        unsigned short* vp = VS + (size_t)ch * VSTR + ks0;
        *(ushort4v*)(vp)      = *(ushort4v*)&v0;
        *(ushort4v*)(vp + 4)  = *((ushort4v*)&v0 + 1);
        *(ushort4v*)(vp + 8)  = *(ushort4v*)&v1;
        *(ushort4v*)(vp + 12) = *((ushort4v*)&v1 + 1);
        *(ushort4v*)(vp + 16) = *(ushort4v*)&v2;
        *(ushort4v*)(vp + 20) = *((ushort4v*)&v2 + 1);
        *(ushort4v*)(vp + 24) = *(ushort4v*)&v3;
        *(ushort4v*)(vp + 28) = *((ushort4v*)&v3 + 1);
        if (tid < 256) {
            unsigned short* p = KL + (size_t)tid * KSTR;
            *(ushort4v*)(p)     = *(ushort4v*)&kA;
            *(ushort4v*)(p + 4) = *((ushort4v*)&kA + 1);
        }
    }
    __syncthreads();                           // the ONLY barrier

    f32x16 o0, o1, zz;
    #pragma unroll
    for (int r = 0; r < 16; ++r) { o0[r] = 0.f; o1[r] = 0.f; zz[r] = 0.f; }
    float s0 = 0.f, s1 = 0.f, s2 = 0.f, s3 = 0.f;

    // preload all kf; issue QK for sub 0
    short4v kfr[8];
    #pragma unroll
    for (int s = 0; s < 8; ++s)
        kfr[s] = *(const short4v*)(KL + (size_t)(s * 32 + l32) * KSTR + h2 * 4);
    f32x16 st0 = MFMA32x8(kfr[0], qf, zz);

    #pragma unroll
    for (int s = 0; s < 8; ++s) {
        f32x16 st1;
        if (s < 7) st1 = MFMA32x8(kfr[s + 1], qf, zz);   // next sub's QK, issued early

        float w[16];
        #pragma unroll
        for (int r = 0; r < 16; ++r) w[r] = EXP2(st0[r]);
        s0 += (w[0] + w[1]) + (w[2] + w[3]);
        s1 += (w[4] + w[5]) + (w[6] + w[7]);
        s2 += (w[8] + w[9]) + (w[10] + w[11]);
        s3 += (w[12] + w[13]) + (w[14] + w[15]);

        union { short4v s; __hip_bfloat162 h[2]; } u[4];
        #pragma unroll
        for (int g = 0; g < 4; ++g) {
            u[g].h[0] = __float22bfloat162_rn(make_float2(w[4 * g],     w[4 * g + 1]));
            u[g].h[1] = __float22bfloat162_rn(make_float2(w[4 * g + 2], w[4 * g + 3]));
        }
        #pragma unroll
        for (int g = 0; g < 4; ++g) {
            int gg = s * 4 + g;
            short4v vf0 = *(const short4v*)(VS + (size_t)(l32)      * VSTR + gg * 8 + h2 * 4);
            short4v vf1 = *(const short4v*)(VS + (size_t)(32 + l32) * VSTR + gg * 8 + h2 * 4);
            o0 = MFMA32x8(u[g].s, vf0, o0);
            o1 = MFMA32x8(u[g].s, vf1, o1);
        }
        st0 = st1;
    }

    // ---- raw-layout full-line stores: uint = bf162(o0[r],o1[r])
    unsigned* au = accb + (((size_t)((b * KS + split) * 128 + qchunk * 8 + wave)) << 10);
    #pragma unroll
    for (int r = 0; r < 16; ++r)
        au[r * 64 + lane] = packu(o0[r], o1[r]);

    float ssum = (s0 + s1) + (s2 + s3);
    ssum += __shfl_xor(ssum, 32);
    if (lane < 32)
        sbuf[(size_t)(b * KS + split) * NN + n0 + l32] = ssum;
}

// ---------------------------------------------------------------------------
// Kernel 3: streaming split-reduce + normalize + residual (unchanged from
// the 101.5us build).  Grid: B*256 = 1024 blocks (16 queries each).
// ---------------------------------------------------------------------------
__global__ __launch_bounds__(256) void norm_kernel(
    const unsigned* __restrict__ accb, const float* __restrict__ sbuf,
    const float* __restrict__ x, const float* __restrict__ gamma,
    float* __restrict__ out)
{
    __shared__ float tile[16 * 65];
    __shared__ float stl[16];
    int blk = blockIdx.x;            // B * 256
    int b = blk >> 8;
    int h = blk & 255;
    int g32 = h >> 1;                // 32-query group
    int qhalf = h & 1;               // low/high 16 queries of the group
    int n0 = g32 * 32 + qhalf * 16;
    int tid = threadIdx.x;

    if (tid < 16) {
        float st = 0.f;
        #pragma unroll
        for (int sp = 0; sp < KS; ++sp)
            st += sbuf[(size_t)(b * KS + sp) * NN + n0 + tid];
        stl[tid] = 1.0f / st;
    }

    int spoff = tid >> 7;            // 0/1: even/odd split of each pass-pair
    int u = tid & 127;
    int rl = u >> 4;                 // r_local 0..7
    int lane0 = (u & 15) * 4;

    float alo[4], ahi[4];
    #pragma unroll
    for (int e = 0; e < 4; ++e) { alo[e] = 0.f; ahi[e] = 0.f; }
    #pragma unroll
    for (int p = 0; p < KS / 2; ++p) {
        int sp = p * 2 + spoff;
        const unsigned* base = accb + (((size_t)((b * KS + sp) * 128 + g32)) << 10)
                             + qhalf * 512;
        uint4 v = *(const uint4*)(base + u * 4);
        unsigned wv[4] = {v.x, v.y, v.z, v.w};
        #pragma unroll
        for (int e = 0; e < 4; ++e) {
            alo[e] += __uint_as_float(wv[e] << 16);
            ahi[e] += __uint_as_float(wv[e] & 0xFFFF0000u);
        }
    }

    #pragma unroll
    for (int e = 0; e < 4; ++e) {
        int lane = lane0 + e;
        int h2 = lane >> 5, l32 = lane & 31;
        int ql = (rl & 3) + 8 * ((rl >> 2) & 1) + 4 * h2;
        if (tid < 128) {
            tile[ql * 65 + l32]      = alo[e];
            tile[ql * 65 + 32 + l32] = ahi[e];
        }
    }
    __syncthreads();
    #pragma unroll
    for (int e = 0; e < 4; ++e) {
        int lane = lane0 + e;
        int h2 = lane >> 5, l32 = lane & 31;
        int ql = (rl & 3) + 8 * ((rl >> 2) & 1) + 4 * h2;
        if (tid >= 128) {
            tile[ql * 65 + l32]      += alo[e];
            tile[ql * 65 + 32 + l32] += ahi[e];
        }
    }
    __syncthreads();

    float gm = gamma[0];
    #pragma unroll
    for (int p2 = 0; p2 < 4; ++p2) {
        int idx = p2 * 256 + tid;
        int c = idx >> 4, ql = idx & 15;
        size_t xi = ((size_t)b * CC + c) * NN + n0 + ql;
        out[xi] = gm * tile[ql * 65 + c] * stl[ql] + x[xi];
    }
}

// ---------------------------------------------------------------------------
extern "C" void kernel_launch(void* const* d_in, const int* in_sizes, int n_in,
                              void* d_out, int out_size, void* d_ws, size_t ws_size,
                              hipStream_t stream)
{
    const float* x     = (const float*)d_in[0];
    const float* Wq    = (const float*)d_in[1];
    const float* bq    = (const float*)d_in[2];
    const float* Wk    = (const float*)d_in[3];
    const float* bk    = (const float*)d_in[4];
    const float* Wv    = (const float*)d_in[5];
    const float* bv    = (const float*)d_in[6];
    const float* gamma = (const float*)d_in[7];
    float* out = (float*)d_out;

    float* ws = (float*)d_ws;
    size_t off = 0;
    unsigned short* qb = (unsigned short*)(ws + off); off += (size_t)BB * NN * DD / 2 + 64;
    unsigned short* kb = (unsigned short*)(ws + off); off += (size_t)BB * NN * DD / 2 + 64;
    unsigned short* vT = (unsigned short*)(ws + off); off += (size_t)BB * CC * NN / 2 + 64;
    unsigned* accb = (unsigned*)(ws + off); off += (size_t)BB * KS * NN * CC / 2;   // 33.5 MB
    float* sbuf = ws + off; off += (size_t)BB * KS * NN;

    qkv_kernel<<<BB * 3 * 32, 256, 0, stream>>>(x, Wq, bq, Wk, bk, Wv, bv, qb, kb, vT);
    flash_kernel<<<BB * 16 * KS, 512, 0, stream>>>(qb, kb, vT, accb, sbuf);
    norm_kernel<<<BB * 256, 256, 0, stream>>>(accb, sbuf, x, gamma, out);
}

// Round 16
// 101.593 us; speedup vs baseline: 1.1950x; 1.0014x over previous
//
#include <hip/hip_runtime.h>
#include <hip/hip_bf16.h>
#include <math.h>

#define BB 4
#define CC 64
#define DD 8
#define NN 4096
#define KS 16
#define KPS (NN / KS)          // 256 keys per split = ONE LDS stage
#define VSTR 260               // VS row stride (elems): 2-way-free b64 reads
#define KSTR 12                // KL row stride (elems)
#define LOG2E 1.44269504088896340736f

typedef __attribute__((ext_vector_type(4))) short short4v;      // 4 bf16
typedef __attribute__((ext_vector_type(4))) unsigned short ushort4v;
typedef __attribute__((ext_vector_type(8))) unsigned short ushort8;  // 16B
typedef __attribute__((ext_vector_type(16))) float f32x16;

#if defined(__HIP_DEVICE_COMPILE__)
  #if __has_builtin(__builtin_amdgcn_mfma_f32_32x32x8bf16_1k)
    #define MFMA32x8(A, B, C) __builtin_amdgcn_mfma_f32_32x32x8bf16_1k(A, B, C, 0, 0, 0)
  #elif __has_builtin(__builtin_amdgcn_mfma_f32_32x32x8_bf16)
    #define MFMA32x8(A, B, C) __builtin_amdgcn_mfma_f32_32x32x8_bf16(A, B, C, 0, 0, 0)
  #else
    #error "no 32x32x8 bf16 MFMA builtin in device pass"
  #endif
  #if __has_builtin(__builtin_amdgcn_exp2f)
    #define EXP2(x) __builtin_amdgcn_exp2f(x)
  #else
    #define EXP2(x) exp2f(x)
  #endif
#else
  static __device__ __host__ inline f32x16 MFMA32x8(short4v, short4v, f32x16 c) { return c; }
  #define EXP2(x) exp2f(x)
#endif

static __device__ inline short4v pack4(float a, float b, float c, float d) {
    union { short4v s; __hip_bfloat162 h[2]; } u;
    u.h[0] = __float22bfloat162_rn(make_float2(a, b));
    u.h[1] = __float22bfloat162_rn(make_float2(c, d));
    return u.s;
}
static __device__ inline unsigned packu(float lo, float hi) {
    union { __hip_bfloat162 h; unsigned u; } t;
    t.h = __float22bfloat162_rn(make_float2(lo, hi));
    return t.u;
}

// ---------------------------------------------------------------------------
// Kernel 1: qkv as MFMA GEMM (unchanged from R8-R15).
// ---------------------------------------------------------------------------
__global__ __launch_bounds__(256) void qkv_kernel(
    const float* __restrict__ x,  const float* __restrict__ Wq, const float* __restrict__ bq,
    const float* __restrict__ Wk, const float* __restrict__ bk,
    const float* __restrict__ Wv, const float* __restrict__ bv,
    unsigned short* __restrict__ qb, unsigned short* __restrict__ kb,
    unsigned short* __restrict__ vT)
{
    __shared__ unsigned short LQ[128 * 8];
    __shared__ unsigned short LK[128 * 8];

    int tid = threadIdx.x;
    int wave = tid >> 6, lane = tid & 63;
    int l32 = lane & 31, h2 = lane >> 5;

    int blk = blockIdx.x;
    int b = blk & (BB - 1);
    int r2 = blk >> 2;
    int rt = r2 % 3;
    int ng = r2 / 3;
    int n0 = ng * 128 + wave * 32;

    short4v af[8];
    #pragma unroll
    for (int s = 0; s < 8; ++s) {
        float4 w4;
        if (rt < 2) {
            w4 = *(const float4*)(Wv + (size_t)(rt * 32 + l32) * CC + s * 8 + 4 * h2);
        } else if (l32 < 8) {
            w4 = *(const float4*)(Wq + (size_t)l32 * CC + s * 8 + 4 * h2);
        } else if (l32 < 16) {
            w4 = *(const float4*)(Wk + (size_t)(l32 - 8) * CC + s * 8 + 4 * h2);
        } else {
            w4 = make_float4(0.f, 0.f, 0.f, 0.f);
        }
        af[s] = pack4(w4.x, w4.y, w4.z, w4.w);
    }

    const float* xb = x + (size_t)b * CC * NN + n0 + l32;
    short4v bf[8];
    #pragma unroll
    for (int s = 0; s < 8; ++s) {
        int c0 = s * 8 + 4 * h2;
        float x0 = xb[(size_t)(c0 + 0) * NN];
        float x1 = xb[(size_t)(c0 + 1) * NN];
        float x2 = xb[(size_t)(c0 + 2) * NN];
        float x3 = xb[(size_t)(c0 + 3) * NN];
        bf[s] = pack4(x0, x1, x2, x3);
    }

    f32x16 acc;
    #pragma unroll
    for (int r = 0; r < 16; ++r) acc[r] = 0.f;
    #pragma unroll
    for (int s = 0; s < 8; ++s)
        acc = MFMA32x8(af[s], bf[s], acc);

    if (rt < 2) {
        #pragma unroll
        for (int r = 0; r < 16; ++r) {
            int row = rt * 32 + (r & 3) + 8 * (r >> 2) + 4 * h2;
            float val = acc[r] + bv[row];
            __hip_bfloat16 hv = __float2bfloat16(val);
            vT[((size_t)b * CC + row) * NN + n0 + l32] = *(unsigned short*)&hv;
        }
    } else {
        short4v qp = pack4((acc[0] + bq[0 + 4 * h2]) * LOG2E,
                           (acc[1] + bq[1 + 4 * h2]) * LOG2E,
                           (acc[2] + bq[2 + 4 * h2]) * LOG2E,
                           (acc[3] + bq[3 + 4 * h2]) * LOG2E);
        short4v kp = pack4(acc[4] + bk[0 + 4 * h2],
                           acc[5] + bk[1 + 4 * h2],
                           acc[6] + bk[2 + 4 * h2],
                           acc[7] + bk[3 + 4 * h2]);
        int nl = wave * 32 + l32;
        *(short4v*)(LQ + (size_t)nl * 8 + 4 * h2) = qp;
        *(short4v*)(LK + (size_t)nl * 8 + 4 * h2) = kp;
        __syncthreads();
        if (tid < 128) {
            ushort8 row = *(const ushort8*)(LQ + (size_t)tid * 8);
            *(ushort8*)(qb + ((size_t)b * NN + ng * 128 + tid) * 8) = row;
        } else {
            int t = tid - 128;
            ushort8 row = *(const ushort8*)(LK + (size_t)t * 8);
            *(ushort8*)(kb + ((size_t)b * NN + ng * 128 + t) * 8) = row;
        }
    }
}

// ---------------------------------------------------------------------------
// Kernel 2: MFMA flash with WAVE DE-PHASING.
// Diagnosis (R10-R15 counters): MfmaUtil/VALUBusy/LDS each match predicted
// busy time (~7/8/5us) but the kernel runs at their SUM (~40us), not their
// max -- after the barrier all 8 waves execute the same unrolled sequence in
// lockstep, so every wave jams the same pipe at the same time (all-exp2,
// then all-MFMA, then all-pack...).  Fix: wave w processes the 8 independent
// subs in rotated order (s+wave)&7, via ADDRESS arithmetic (LDS reads with
// runtime sub index -- no register-array dynamic indexing).  At any instant
// the 8 waves occupy different phases -> trans/MFMA/VALU/LDS overlap.
// Everything else byte-identical to the 101.5us build.
// Grid: BB * 16 qchunks * KS = 1024 blocks, 512 thr.
// ---------------------------------------------------------------------------
__global__ __launch_bounds__(512, 4) void flash_kernel(
    const unsigned short* __restrict__ qb, const unsigned short* __restrict__ kb,
    const unsigned short* __restrict__ vT, unsigned* __restrict__ accb,
    float* __restrict__ sbuf)
{
    __shared__ unsigned short VS[64 * VSTR];   // 256 keys x 64 ch, 33280 B
    __shared__ unsigned short KL[256 * KSTR];  //  6144 B
    int tid = threadIdx.x;
    int wave = tid >> 6, lane = tid & 63;
    int l32 = lane & 31, h2 = lane >> 5;

    int blk = blockIdx.x;            // batch in low 2 bits -> XCD locality
    int b = blk & (BB - 1);
    int rest = blk >> 2;
    int split = rest & (KS - 1);
    int qchunk = rest >> 4;
    int n0 = qchunk * 256 + wave * 32;

    short4v qf = *(const short4v*)(qb + ((size_t)b * NN + n0 + l32) * DD + h2 * 4);

    const unsigned short* kbb = kb + (size_t)b * NN * DD;
    const unsigned short* vbb = vT + (size_t)b * CC * NN;
    int m0 = split * KPS;

    // ---- stage: thread t -> channel t>>3, key segment (t&7)*32 (32 keys)
    int ch = tid >> 3, ks0 = (tid & 7) * 32;
    {
        const unsigned short* vg = vbb + (size_t)ch * NN + m0 + ks0;
        ushort8 v0 = *(const ushort8*)(vg);
        ushort8 v1 = *(const ushort8*)(vg + 8);
        ushort8 v2 = *(const ushort8*)(vg + 16);
        ushort8 v3 = *(const ushort8*)(vg + 24);
        ushort8 kA = {0,0,0,0,0,0,0,0};
        if (tid < 256) kA = *(const ushort8*)(kbb + (size_t)(m0 + tid) * DD);

        unsigned short* vp = VS + (size_t)ch * VSTR + ks0;
        *(ushort4v*)(vp)      = *(ushort4v*)&v0;
        *(ushort4v*)(vp + 4)  = *((ushort4v*)&v0 + 1);
        *(ushort4v*)(vp + 8)  = *(ushort4v*)&v1;
        *(ushort4v*)(vp + 12) = *((ushort4v*)&v1 + 1);
        *(ushort4v*)(vp + 16) = *(ushort4v*)&v2;
        *(ushort4v*)(vp + 20) = *((ushort4v*)&v2 + 1);
        *(ushort4v*)(vp + 24) = *(ushort4v*)&v3;
        *(ushort4v*)(vp + 28) = *((ushort4v*)&v3 + 1);
        if (tid < 256) {
            unsigned short* p = KL + (size_t)tid * KSTR;
            *(ushort4v*)(p)     = *(ushort4v*)&kA;
            *(ushort4v*)(p + 4) = *((ushort4v*)&kA + 1);
        }
    }
    __syncthreads();                           // the ONLY barrier

    f32x16 o0, o1, zz;
    #pragma unroll
    for (int r = 0; r < 16; ++r) { o0[r] = 0.f; o1[r] = 0.f; zz[r] = 0.f; }
    float s0 = 0.f, s1 = 0.f, s2 = 0.f, s3 = 0.f;

    // de-phased sub order: wave w starts at sub w (runtime offset ->
    // address arithmetic only).  2-deep pipeline: next sub's kf+QK early.
    int sw = wave;                             // phase offset 0..7
    short4v kf0 = *(const short4v*)(KL + (size_t)(sw * 32 + l32) * KSTR + h2 * 4);
    f32x16 st0 = MFMA32x8(kf0, qf, zz);

    #pragma unroll
    for (int s = 0; s < 8; ++s) {
        int se = (s + sw) & 7;                 // this sub
        int sn = (s + 1 + sw) & 7;             // next sub
        f32x16 st1;
        if (s < 7) {
            short4v kf1 = *(const short4v*)(KL + (size_t)(sn * 32 + l32) * KSTR + h2 * 4);
            st1 = MFMA32x8(kf1, qf, zz);       // next sub's QK, issued early
        }

        float w[16];
        #pragma unroll
        for (int r = 0; r < 16; ++r) w[r] = EXP2(st0[r]);
        s0 += (w[0] + w[1]) + (w[2] + w[3]);
        s1 += (w[4] + w[5]) + (w[6] + w[7]);
        s2 += (w[8] + w[9]) + (w[10] + w[11]);
        s3 += (w[12] + w[13]) + (w[14] + w[15]);

        union { short4v s; __hip_bfloat162 h[2]; } u[4];
        #pragma unroll
        for (int g = 0; g < 4; ++g) {
            u[g].h[0] = __float22bfloat162_rn(make_float2(w[4 * g],     w[4 * g + 1]));
            u[g].h[1] = __float22bfloat162_rn(make_float2(w[4 * g + 2], w[4 * g + 3]));
        }
        #pragma unroll
        for (int g = 0; g < 4; ++g) {
            int gg = se * 4 + g;
            short4v vf0 = *(const short4v*)(VS + (size_t)(l32)      * VSTR + gg * 8 + h2 * 4);
            short4v vf1 = *(const short4v*)(VS + (size_t)(32 + l32) * VSTR + gg * 8 + h2 * 4);
            o0 = MFMA32x8(u[g].s, vf0, o0);
            o1 = MFMA32x8(u[g].s, vf1, o1);
        }
        st0 = st1;
    }

    // ---- raw-layout full-line stores: uint = bf162(o0[r],o1[r])
    unsigned* au = accb + (((size_t)((b * KS + split) * 128 + qchunk * 8 + wave)) << 10);
    #pragma unroll
    for (int r = 0; r < 16; ++r)
        au[r * 64 + lane] = packu(o0[r], o1[r]);

    float ssum = (s0 + s1) + (s2 + s3);
    ssum += __shfl_xor(ssum, 32);
    if (lane < 32)
        sbuf[(size_t)(b * KS + split) * NN + n0 + l32] = ssum;
}

// ---------------------------------------------------------------------------
// Kernel 3: streaming split-reduce + normalize + residual (unchanged from
// the 101.5us build).  Grid: B*256 = 1024 blocks (16 queries each).
// ---------------------------------------------------------------------------
__global__ __launch_bounds__(256) void norm_kernel(
    const unsigned* __restrict__ accb, const float* __restrict__ sbuf,
    const float* __restrict__ x, const float* __restrict__ gamma,
    float* __restrict__ out)
{
    __shared__ float tile[16 * 65];
    __shared__ float stl[16];
    int blk = blockIdx.x;            // B * 256
    int b = blk >> 8;
    int h = blk & 255;
    int g32 = h >> 1;                // 32-query group
    int qhalf = h & 1;               // low/high 16 queries of the group
    int n0 = g32 * 32 + qhalf * 16;
    int tid = threadIdx.x;

    if (tid < 16) {
        float st = 0.f;
        #pragma unroll
        for (int sp = 0; sp < KS; ++sp)
            st += sbuf[(size_t)(b * KS + sp) * NN + n0 + tid];
        stl[tid] = 1.0f / st;
    }

    int spoff = tid >> 7;            // 0/1: even/odd split of each pass-pair
    int u = tid & 127;
    int rl = u >> 4;                 // r_local 0..7
    int lane0 = (u & 15) * 4;

    float alo[4], ahi[4];
    #pragma unroll
    for (int e = 0; e < 4; ++e) { alo[e] = 0.f; ahi[e] = 0.f; }
    #pragma unroll
    for (int p = 0; p < KS / 2; ++p) {
        int sp = p * 2 + spoff;
        const unsigned* base = accb + (((size_t)((b * KS + sp) * 128 + g32)) << 10)
                             + qhalf * 512;
        uint4 v = *(const uint4*)(base + u * 4);
        unsigned wv[4] = {v.x, v.y, v.z, v.w};
        #pragma unroll
        for (int e = 0; e < 4; ++e) {
            alo[e] += __uint_as_float(wv[e] << 16);
            ahi[e] += __uint_as_float(wv[e] & 0xFFFF0000u);
        }
    }

    #pragma unroll
    for (int e = 0; e < 4; ++e) {
        int lane = lane0 + e;
        int h2 = lane >> 5, l32 = lane & 31;
        int ql = (rl & 3) + 8 * ((rl >> 2) & 1) + 4 * h2;
        if (tid < 128) {
            tile[ql * 65 + l32]      = alo[e];
            tile[ql * 65 + 32 + l32] = ahi[e];
        }
    }
    __syncthreads();
    #pragma unroll
    for (int e = 0; e < 4; ++e) {
        int lane = lane0 + e;
        int h2 = lane >> 5, l32 = lane & 31;
        int ql = (rl & 3) + 8 * ((rl >> 2) & 1) + 4 * h2;
        if (tid >= 128) {
            tile[ql * 65 + l32]      += alo[e];
            tile[ql * 65 + 32 + l32] += ahi[e];
        }
    }
    __syncthreads();

    float gm = gamma[0];
    #pragma unroll
    for (int p2 = 0; p2 < 4; ++p2) {
        int idx = p2 * 256 + tid;
        int c = idx >> 4, ql = idx & 15;
        size_t xi = ((size_t)b * CC + c) * NN + n0 + ql;
        out[xi] = gm * tile[ql * 65 + c] * stl[ql] + x[xi];
    }
}

// ---------------------------------------------------------------------------
extern "C" void kernel_launch(void* const* d_in, const int* in_sizes, int n_in,
                              void* d_out, int out_size, void* d_ws, size_t ws_size,
                              hipStream_t stream)
{
    const float* x     = (const float*)d_in[0];
    const float* Wq    = (const float*)d_in[1];
    const float* bq    = (const float*)d_in[2];
    const float* Wk    = (const float*)d_in[3];
    const float* bk    = (const float*)d_in[4];
    const float* Wv    = (const float*)d_in[5];
    const float* bv    = (const float*)d_in[6];
    const float* gamma = (const float*)d_in[7];
    float* out = (float*)d_out;

    float* ws = (float*)d_ws;
    size_t off = 0;
    unsigned short* qb = (unsigned short*)(ws + off); off += (size_t)BB * NN * DD / 2 + 64;
    unsigned short* kb = (unsigned short*)(ws + off); off += (size_t)BB * NN * DD / 2 + 64;
    unsigned short* vT = (unsigned short*)(ws + off); off += (size_t)BB * CC * NN / 2 + 64;
    unsigned* accb = (unsigned*)(ws + off); off += (size_t)BB * KS * NN * CC / 2;   // 33.5 MB
    float* sbuf = ws + off; off += (size_t)BB * KS * NN;

    qkv_kernel<<<BB * 3 * 32, 256, 0, stream>>>(x, Wq, bq, Wk, bk, Wv, bv, qb, kb, vT);
    flash_kernel<<<BB * 16 * KS, 512, 0, stream>>>(qb, kb, vT, accb, sbuf);
    norm_kernel<<<BB * 256, 256, 0, stream>>>(accb, sbuf, x, gamma, out);
}